// Round 3
// baseline (880.235 us; speedup 1.0000x reference)
//
#include <hip/hip_runtime.h>
#include <hip/hip_bf16.h>

using short8 = __attribute__((ext_vector_type(8))) short;
using f32x4  = __attribute__((ext_vector_type(4))) float;

#define K1P 168   // padded K=160 row stride (bf16) for edge MLP layer 1
#define DP  72    // padded 64 row stride for layer 2
#define KLP 136   // padded K=128 row stride for LSTM
#define ACCP 66   // accH row stride (floats)

__device__ __forceinline__ unsigned short f2bf(float f) {
  unsigned u = __float_as_uint(f);
  u += 0x7FFFu + ((u >> 16) & 1u);
  return (unsigned short)(u >> 16);
}
__device__ __forceinline__ unsigned pack2(float a, float b) {
  return (unsigned)f2bf(a) | ((unsigned)f2bf(b) << 16);
}
__device__ __forceinline__ float sigm(float x) { return 1.f / (1.f + __expf(-x)); }

// ---------------- weight prep: transpose + bf16 cast ----------------
__global__ __launch_bounds__(256) void prep_weights(
    const float* __restrict__ W1_0, const float* __restrict__ W2_0,
    const float* __restrict__ Wih0, const float* __restrict__ Whh0,
    const float* __restrict__ bih0, const float* __restrict__ bhh0,
    const float* __restrict__ W1_1, const float* __restrict__ W2_1,
    const float* __restrict__ Wih1, const float* __restrict__ Whh1,
    const float* __restrict__ bih1, const float* __restrict__ bhh1,
    const float* __restrict__ gmW, const float* __restrict__ fmW,
    unsigned short* __restrict__ W1T,  // [2][64*160]  (out-major, k inner)
    unsigned short* __restrict__ W2T,  // [2][64*64]
    unsigned short* __restrict__ WcT,  // [2][256*128]
    float* __restrict__ bG,            // [2][256]
    unsigned short* __restrict__ WrT)  // [128][64] readout
{
  int t = blockIdx.x * 256 + threadIdx.x;
  const int per = 10240 + 4096 + 32768 + 256;  // 47360
  if (t >= 2 * per + 8192) return;
  if (t >= 2 * per) {
    int r2 = t - 2 * per;
    int o = r2 >> 6, k = r2 & 63;
    float v = 0.f;
    if (o < 50) v = gmW[k * 50 + o];
    else if (o >= 64 && o < 114) v = fmW[k * 50 + (o - 64)];
    WrT[o * 64 + k] = f2bf(v);
    return;
  }
  int step = t / per, r = t % per;
  const float* W1  = step ? W1_1 : W1_0;
  const float* W2  = step ? W2_1 : W2_0;
  const float* Wih = step ? Wih1 : Wih0;
  const float* Whh = step ? Whh1 : Whh0;
  const float* bih = step ? bih1 : bih0;
  const float* bhh = step ? bhh1 : bhh0;
  if (r < 10240) {
    int o = r / 160, k = r % 160;
    W1T[step * 10240 + o * 160 + k] = f2bf(W1[k * 64 + o]);
  } else if (r < 14336) {
    int q = r - 10240; int o = q / 64, k = q % 64;
    W2T[step * 4096 + o * 64 + k] = f2bf(W2[k * 64 + o]);
  } else if (r < 47104) {
    int q = r - 14336; int o = q / 128, k = q % 128;
    float v = (k < 64) ? Wih[k * 256 + o] : Whh[(k - 64) * 256 + o];
    WcT[step * 32768 + o * 128 + k] = f2bf(v);
  } else {
    int g = r - 47104;
    bG[step * 256 + g] = bih[g] + bhh[g];
  }
}

__global__ __launch_bounds__(256) void convert_x(
    const float* __restrict__ x, unsigned short* __restrict__ xb, int n)
{
  int i = blockIdx.x * 256 + threadIdx.x;
  if (i < n) xb[i] = f2bf(x[i]);
}

// ---------------- sort edges by dst: hist -> scan -> scatter ----------------
__global__ __launch_bounds__(256) void hist_kernel(
    const int* __restrict__ dstI, int* __restrict__ hist, int E)
{
  int e = blockIdx.x * 256 + threadIdx.x;
  if (e < E) atomicAdd(&hist[dstI[e]], 1);
}

__global__ __launch_bounds__(1024) void scan_kernel(
    const int* __restrict__ hist, int* __restrict__ base,
    int* __restrict__ cursor, int n, int E)
{
  __shared__ int part[1024];
  int t = threadIdx.x;
  int C = (n + 1023) >> 10;
  int c0 = t * C;
  int s = 0;
  for (int i = 0; i < C; ++i) {
    int idx = c0 + i;
    if (idx < n) s += hist[idx];
  }
  part[t] = s;
  __syncthreads();
  for (int off = 1; off < 1024; off <<= 1) {
    int v = (t >= off) ? part[t - off] : 0;
    __syncthreads();
    part[t] += v;
    __syncthreads();
  }
  int run = (t > 0) ? part[t - 1] : 0;
  for (int i = 0; i < C; ++i) {
    int idx = c0 + i;
    if (idx < n) {
      base[idx] = run;
      cursor[idx] = run;
      run += hist[idx];
    }
  }
  if (t == 0) base[n] = E;
}

__global__ __launch_bounds__(256) void scatter_kernel(
    const int* __restrict__ dstI, int* __restrict__ cursor,
    int* __restrict__ eidS, int E)
{
  int e = blockIdx.x * 256 + threadIdx.x;
  if (e < E) {
    int d = dstI[e];
    int p = atomicAdd(&cursor[d], 1);
    eidS[p] = e;
  }
}

// ---------------- edge MLP, dst-segmented (no global atomics) ----------------
// block b owns dst nodes [64b,64b+64) and all their (sorted) edges.
// accumulates relu(h1) per local dst in LDS fp32, then (sum)@W2 + deg*b2 -> aggrB (bf16)
__global__ __launch_bounds__(256) void edge_mlp_seg(
    const unsigned short* __restrict__ xb,   // [N][64] bf16
    const float* __restrict__ ea,            // [E][32] f32
    const int* __restrict__ srcI,
    const int* __restrict__ dstI,
    const int* __restrict__ eidS,            // [E] edge ids sorted by dst
    const int* __restrict__ base,            // [N+1]
    const unsigned short* __restrict__ W1T,  // [64][160] bf16 out-major
    const unsigned short* __restrict__ W2T,  // [64][64]
    const float* __restrict__ b1,
    const float* __restrict__ b2,
    unsigned short* __restrict__ aggrB,      // [N][64] bf16
    int nNodes)
{
  __shared__ unsigned short sM[64 * K1P];
  __shared__ unsigned short sW1[64 * K1P];
  __shared__ unsigned short sW2[64 * DP];
  __shared__ float accH[65 * ACCP];          // row 64 = dummy for masked edges
  __shared__ int   sLdst[64];
  __shared__ float sB1[64], sB2[64];
  const int t = threadIdx.x;

  // stage weights + zero accumulator
  {
    const uint4* gw1 = (const uint4*)W1T;   // 1280 uint4, 20/row
    uint4* lw1 = (uint4*)sW1;               // 21/row (padded)
    #pragma unroll
    for (int p = 0; p < 5; ++p) {
      int idx = t + p * 256;
      int o = idx / 20, s = idx % 20;
      lw1[o * 21 + s] = gw1[idx];
    }
    const uint4* gw2 = (const uint4*)W2T;   // 512 uint4, 8/row
    uint4* lw2 = (uint4*)sW2;               // 9/row
    #pragma unroll
    for (int p = 0; p < 2; ++p) {
      int idx = t + p * 256;
      int o = idx / 8, s = idx % 8;
      lw2[o * 9 + s] = gw2[idx];
    }
    if (t < 64) { sB1[t] = b1[t]; sB2[t] = b2[t]; }
    for (int i = t; i < 65 * ACCP; i += 256) accH[i] = 0.f;
  }

  const int n0 = blockIdx.x * 64;
  const int eStart = base[n0];
  const int eEnd   = base[min(n0 + 64, nNodes)];
  __syncthreads();

  const int w = t >> 6, l = t & 63, quad = l >> 4, lr = l & 15;
  const int row0 = w * 16;
  const int el = t >> 2, q = t & 3;

  for (int c0 = eStart; c0 < eEnd; c0 += 64) {
    int ep = c0 + el;
    bool valid = ep < eEnd;
    int eid = valid ? eidS[ep] : 0;
    int d_n = valid ? dstI[eid] : 0;
    int s_n = srcI[eid];
    if (q == 0) sLdst[el] = valid ? (d_n - n0) : 64;
    uint4* pm = (uint4*)sM + el * 21;
    const uint4* pd = (const uint4*)xb + (long long)d_n * 8;
    const uint4* ps = (const uint4*)xb + (long long)s_n * 8;
    pm[q]      = pd[q];
    pm[q + 4]  = pd[q + 4];
    pm[8 + q]  = ps[q];
    pm[12 + q] = ps[q + 4];
    const float4* pe = (const float4*)ea + (long long)eid * 8;
    float4 f0 = pe[q * 2], f1 = pe[q * 2 + 1];
    pm[16 + q] = make_uint4(pack2(f0.x, f0.y), pack2(f0.z, f0.w),
                            pack2(f1.x, f1.y), pack2(f1.z, f1.w));
    __syncthreads();

    // GEMM1: h1[64x64] = relu(m[64x160] @ W1 + b1)
    f32x4 acc[4] = {};
    #pragma unroll
    for (int kc = 0; kc < 5; ++kc) {
      short8 aF = *(const short8*)(sM + (row0 + lr) * K1P + kc * 32 + quad * 8);
      #pragma unroll
      for (int n = 0; n < 4; ++n) {
        short8 bF = *(const short8*)(sW1 + (n * 16 + lr) * K1P + kc * 32 + quad * 8);
        acc[n] = __builtin_amdgcn_mfma_f32_16x16x32_bf16(aF, bF, acc[n], 0, 0, 0);
      }
    }

    // relu + segmented accumulate into accH (LDS atomics, in-lane run merge)
    int r0g = row0 + quad * 4;
    int ld0 = sLdst[r0g], ld1 = sLdst[r0g + 1], ld2 = sLdst[r0g + 2], ld3 = sLdst[r0g + 3];
    bool same = (ld0 == ld1) && (ld1 == ld2) && (ld2 == ld3);
    #pragma unroll
    for (int n = 0; n < 4; ++n) {
      int col = n * 16 + lr;
      float bb = sB1[col];
      float v0 = fmaxf(acc[n][0] + bb, 0.f);
      float v1 = fmaxf(acc[n][1] + bb, 0.f);
      float v2 = fmaxf(acc[n][2] + bb, 0.f);
      float v3 = fmaxf(acc[n][3] + bb, 0.f);
      if (same) {
        atomicAdd(&accH[ld0 * ACCP + col], (v0 + v1) + (v2 + v3));
      } else {
        atomicAdd(&accH[ld0 * ACCP + col], v0);
        atomicAdd(&accH[ld1 * ACCP + col], v1);
        atomicAdd(&accH[ld2 * ACCP + col], v2);
        atomicAdd(&accH[ld3 * ACCP + col], v3);
      }
    }
    __syncthreads();
  }

  // epilogue: bf16-cast accumulated hidden, GEMM2 with W2, +deg*b2, store
  unsigned short* sHb = sM;  // reuse
  for (int i = t; i < 64 * 64; i += 256) {
    int rr = i >> 6, cc = i & 63;
    sHb[rr * DP + cc] = f2bf(accH[rr * ACCP + cc]);
  }
  __syncthreads();

  f32x4 acc2[4] = {};
  #pragma unroll
  for (int kc = 0; kc < 2; ++kc) {
    short8 aF = *(const short8*)(sHb + (row0 + lr) * DP + kc * 32 + quad * 8);
    #pragma unroll
    for (int n = 0; n < 4; ++n) {
      short8 bF = *(const short8*)(sW2 + (n * 16 + lr) * DP + kc * 32 + quad * 8);
      acc2[n] = __builtin_amdgcn_mfma_f32_16x16x32_bf16(aF, bF, acc2[n], 0, 0, 0);
    }
  }
  #pragma unroll
  for (int n = 0; n < 4; ++n) {
    int col = n * 16 + lr;
    #pragma unroll
    for (int r = 0; r < 4; ++r) {
      int rr = row0 + quad * 4 + r;
      int node = n0 + rr;
      if (node < nNodes) {
        int deg = base[node + 1] - base[node];
        float vv = acc2[n][r] + (float)deg * sB2[col];
        aggrB[(long long)node * 64 + col] = f2bf(vv);
      }
    }
  }
}

// ---------------- LSTM cell v2: whole Wc resident in LDS, single barrier ----------------
__global__ __launch_bounds__(256) void lstm2(
    const float* __restrict__ xin,
    const unsigned short* __restrict__ ainB,  // [N][64] bf16
    float* __restrict__ cbuf,
    const unsigned short* __restrict__ WcT,   // [256][128] bf16 out-major
    const float* __restrict__ bG,             // [256]
    float* __restrict__ xout,
    unsigned short* __restrict__ xbf_out,     // may be null
    int nNodes)
{
  __shared__ unsigned short sIn[64 * KLP];    // 17.4 KB
  __shared__ unsigned short sW[256 * KLP];    // 69.6 KB
  __shared__ float sBG[256];
  const int t = threadIdx.x;
  sBG[t] = bG[t];

  // stage all 256 output rows of Wc: 4096 uint4
  {
    const uint4* gw = (const uint4*)WcT;  // 16 uint4/row
    uint4* lw = (uint4*)sW;               // 17/row padded
    #pragma unroll
    for (int p = 0; p < 16; ++p) {
      int idx = t + p * 256;
      int o = idx >> 4, s = idx & 15;
      lw[o * 17 + s] = gw[idx];
    }
  }

  const int base_n = blockIdx.x * 64;
  const int nl = t >> 2, q = t & 3;
  const int node = base_n + nl;
  if (node < nNodes) {
    const float4* px = (const float4*)(xin + (long long)node * 64);
    #pragma unroll
    for (int j = 0; j < 4; ++j) {
      int jj = q * 4 + j;
      float4 v = px[jj];
      *(uint2*)(sIn + nl * KLP + jj * 4) = make_uint2(pack2(v.x, v.y), pack2(v.z, v.w));
    }
    const uint4* pa = (const uint4*)(ainB + (long long)node * 64);
    uint4* da = (uint4*)(sIn + nl * KLP + 64);
    da[q * 2]     = pa[q * 2];
    da[q * 2 + 1] = pa[q * 2 + 1];
  } else {
    #pragma unroll
    for (int j = 0; j < 4; ++j) {
      int jj = q * 4 + j;
      *(uint2*)(sIn + nl * KLP + jj * 4) = make_uint2(0, 0);
    }
    uint4* da = (uint4*)(sIn + nl * KLP + 64);
    da[q * 2]     = make_uint4(0, 0, 0, 0);
    da[q * 2 + 1] = make_uint4(0, 0, 0, 0);
  }
  __syncthreads();

  const int w = t >> 6, l = t & 63, quad = l >> 4, lr = l & 15;
  const int row0 = w * 16;
  f32x4 acc[16] = {};
  #pragma unroll
  for (int grp = 0; grp < 4; ++grp) {
    #pragma unroll
    for (int kc = 0; kc < 4; ++kc) {
      short8 aF = *(const short8*)(sIn + (row0 + lr) * KLP + kc * 32 + quad * 8);
      #pragma unroll
      for (int nt = 0; nt < 4; ++nt) {
        short8 bF = *(const short8*)(sW + (grp * 64 + nt * 16 + lr) * KLP + kc * 32 + quad * 8);
        acc[grp * 4 + nt] = __builtin_amdgcn_mfma_f32_16x16x32_bf16(aF, bF, acc[grp * 4 + nt], 0, 0, 0);
      }
    }
  }

  #pragma unroll
  for (int nt = 0; nt < 4; ++nt) {
    #pragma unroll
    for (int r = 0; r < 4; ++r) {
      int node2 = base_n + row0 + quad * 4 + r;
      if (node2 < nNodes) {
        int col = nt * 16 + lr;
        long long off = (long long)node2 * 64 + col;
        float iv = acc[nt][r]      + sBG[col];
        float fv = acc[4 + nt][r]  + sBG[64 + col];
        float gv = acc[8 + nt][r]  + sBG[128 + col];
        float ov = acc[12 + nt][r] + sBG[192 + col];
        float cOld = cbuf[off];
        float cN = sigm(fv) * cOld + sigm(iv) * tanhf(gv);
        float hN = sigm(ov) * tanhf(cN);
        cbuf[off] = cN;
        xout[off] = hN;
        if (xbf_out) xbf_out[off] = f2bf(hN);
      }
    }
  }
}

// ---------------- readout (MFMA) ----------------
__global__ __launch_bounds__(256) void readout(
    const float* __restrict__ x,
    const unsigned short* __restrict__ WrT,
    const float* __restrict__ gb, const float* __restrict__ fb,
    float* __restrict__ out, int nNodes)
{
  __shared__ unsigned short sX[64 * 72];
  __shared__ unsigned short sW[128 * 72];
  __shared__ float sOut[4][64];
  __shared__ float sGb[64], sFb[64];
  const int t = threadIdx.x;
  {
    const uint4* gw = (const uint4*)WrT;  // 1024 uint4
    uint4* lw = (uint4*)sW;               // 9/row padded
    #pragma unroll
    for (int p = 0; p < 4; ++p) {
      int idx = t + p * 256;
      int o = idx >> 3, s = idx & 7;
      lw[o * 9 + s] = gw[idx];
    }
    if (t < 50)      { sGb[t] = gb[t]; sFb[t] = fb[t]; }
    else if (t < 64) { sGb[t] = 0.f;   sFb[t] = 0.f; }
  }
  const int base = blockIdx.x * 64;
  const int nl = t >> 2, q = t & 3;
  const int node = base + nl;
  {
    uint2* dst = (uint2*)(sX + nl * 72 + q * 16);
    if (node < nNodes) {
      const float4* px = (const float4*)(x + (long long)node * 64) + q * 4;
      #pragma unroll
      for (int j = 0; j < 4; ++j) {
        float4 v = px[j];
        dst[j] = make_uint2(pack2(v.x, v.y), pack2(v.z, v.w));
      }
    } else {
      #pragma unroll
      for (int j = 0; j < 4; ++j) dst[j] = make_uint2(0, 0);
    }
  }
  __syncthreads();

  const int w = t >> 6, l = t & 63, quad = l >> 4, lr = l & 15;
  f32x4 acc[8] = {};
  #pragma unroll
  for (int kc = 0; kc < 2; ++kc) {
    short8 aF = *(const short8*)(sX + (w * 16 + lr) * 72 + kc * 32 + quad * 8);
    #pragma unroll
    for (int n = 0; n < 8; ++n) {
      short8 bF = *(const short8*)(sW + (n * 16 + lr) * 72 + kc * 32 + quad * 8);
      acc[n] = __builtin_amdgcn_mfma_f32_16x16x32_bf16(aF, bF, acc[n], 0, 0, 0);
    }
  }
  #pragma unroll
  for (int n = 0; n < 4; ++n) {
    float val = 0.f;
    #pragma unroll
    for (int r = 0; r < 4; ++r) {
      int nd = base + w * 16 + quad * 4 + r;
      if (nd < nNodes) {
        int jj = n * 16 + lr;
        float gv = sigm(acc[n][r] + sGb[jj]);
        float fv = acc[n + 4][r] + sFb[jj];
        val += gv * fv;
      }
    }
    val += __shfl_xor(val, 16);
    val += __shfl_xor(val, 32);
    if (quad == 0) sOut[w][n * 16 + lr] = val;
  }
  __syncthreads();
  if (t < 50) {
    float s = sOut[0][t] + sOut[1][t] + sOut[2][t] + sOut[3][t];
    unsafeAtomicAdd(&out[t], s);
  }
}

extern "C" void kernel_launch(void* const* d_in, const int* in_sizes, int n_in,
                              void* d_out, int out_size, void* d_ws, size_t ws_size,
                              hipStream_t stream)
{
  const float* x      = (const float*)d_in[0];
  const float* ea     = (const float*)d_in[1];
  const int*   ei     = (const int*)d_in[2];
  const float* fe0_W1 = (const float*)d_in[3];
  const float* fe0_b1 = (const float*)d_in[4];
  const float* fe0_W2 = (const float*)d_in[5];
  const float* fe0_b2 = (const float*)d_in[6];
  const float* l0_Wih = (const float*)d_in[7];
  const float* l0_Whh = (const float*)d_in[8];
  const float* l0_bih = (const float*)d_in[9];
  const float* l0_bhh = (const float*)d_in[10];
  const float* fe1_W1 = (const float*)d_in[11];
  const float* fe1_b1 = (const float*)d_in[12];
  const float* fe1_W2 = (const float*)d_in[13];
  const float* fe1_b2 = (const float*)d_in[14];
  const float* l1_Wih = (const float*)d_in[15];
  const float* l1_Whh = (const float*)d_in[16];
  const float* l1_bih = (const float*)d_in[17];
  const float* l1_bhh = (const float*)d_in[18];
  const float* gm_W   = (const float*)d_in[19];
  const float* gm_b   = (const float*)d_in[20];
  const float* fm_W   = (const float*)d_in[21];
  const float* fm_b   = (const float*)d_in[22];

  const int N = in_sizes[0] / 64;    // 50000
  const int E = in_sizes[1] / 32;    // 800000
  const int* srcI = ei;
  const int* dstI = ei + E;

  char* ws = (char*)d_ws;
  unsigned short* xb    = (unsigned short*)(ws + 0);         // 6,400,000
  float*          x1    = (float*)(ws + 6400000);            // 12,800,000
  unsigned short* aggrB = (unsigned short*)(ws + 19200000);  // 6,400,000
  float*          cbuf  = (float*)(ws + 25600000);           // 12,800,000
  int*            eidS  = (int*)(ws + 38400000);             // 3,200,000
  int*            baseA = (int*)(ws + 41600000);             // 200,016
  int*            curA  = (int*)(ws + 41800064);             // 200,000
  int*            histA = (int*)(ws + 42000128);             // 200,000
  unsigned short* W1T   = (unsigned short*)(ws + 42200192);  // 40,960
  unsigned short* W2T   = (unsigned short*)(ws + 42241152);  // 16,384
  unsigned short* WcT   = (unsigned short*)(ws + 42257536);  // 131,072
  float*          bG    = (float*)(ws + 42388608);           // 2,048
  unsigned short* WrT   = (unsigned short*)(ws + 42390656);  // 16,384

  hipMemsetAsync(d_out, 0, out_size * sizeof(float), stream);
  hipMemsetAsync(cbuf, 0, (size_t)N * 64 * 4, stream);
  hipMemsetAsync(histA, 0, (size_t)N * 4, stream);

  prep_weights<<<(2 * 47360 + 8192 + 255) / 256, 256, 0, stream>>>(
      fe0_W1, fe0_W2, l0_Wih, l0_Whh, l0_bih, l0_bhh,
      fe1_W1, fe1_W2, l1_Wih, l1_Whh, l1_bih, l1_bhh,
      gm_W, fm_W, W1T, W2T, WcT, bG, WrT);
  convert_x<<<(N * 64 + 255) / 256, 256, 0, stream>>>(x, xb, N * 64);

  // sort edges by dst (dst identical for both steps)
  hist_kernel<<<(E + 255) / 256, 256, 0, stream>>>(dstI, histA, E);
  scan_kernel<<<1, 1024, 0, stream>>>(histA, baseA, curA, N, E);
  scatter_kernel<<<(E + 255) / 256, 256, 0, stream>>>(dstI, curA, eidS, E);

  const int nodeBlocks = (N + 63) / 64;

  // step 0
  edge_mlp_seg<<<nodeBlocks, 256, 0, stream>>>(xb, ea, srcI, dstI, eidS, baseA,
                                               W1T, W2T, fe0_b1, fe0_b2, aggrB, N);
  lstm2<<<nodeBlocks, 256, 0, stream>>>(x, aggrB, cbuf, WcT, bG, x1, xb, N);

  // step 1
  edge_mlp_seg<<<nodeBlocks, 256, 0, stream>>>(xb, ea, srcI, dstI, eidS, baseA,
                                               W1T + 10240, W2T + 4096,
                                               fe1_b1, fe1_b2, aggrB, N);
  lstm2<<<nodeBlocks, 256, 0, stream>>>(x1, aggrB, cbuf, WcT + 32768, bG + 256,
                                        x1, nullptr, N);

  readout<<<nodeBlocks, 256, 0, stream>>>(x1, WrT, gm_b, fm_b, (float*)d_out, N);
}

// Round 4
// 608.615 us; speedup vs baseline: 1.4463x; 1.4463x over previous
//
#include <hip/hip_runtime.h>
#include <hip/hip_bf16.h>

using short8 = __attribute__((ext_vector_type(8))) short;
using f32x4  = __attribute__((ext_vector_type(4))) float;

#define K1P 168   // padded K=160 row stride (bf16) for edge MLP layer 1
#define KLP 136   // padded K=128 row stride for LSTM

__device__ __forceinline__ unsigned short f2bf(float f) {
  unsigned u = __float_as_uint(f);
  u += 0x7FFFu + ((u >> 16) & 1u);
  return (unsigned short)(u >> 16);
}
__device__ __forceinline__ unsigned pack2(float a, float b) {
  return (unsigned)f2bf(a) | ((unsigned)f2bf(b) << 16);
}
#if __has_builtin(__builtin_amdgcn_rcpf)
__device__ __forceinline__ float fast_rcp(float x) { return __builtin_amdgcn_rcpf(x); }
#else
__device__ __forceinline__ float fast_rcp(float x) { return 1.f / x; }
#endif
__device__ __forceinline__ float sigm(float x) { return fast_rcp(1.f + __expf(-x)); }
__device__ __forceinline__ float tanh_f(float x) { return fmaf(2.f, sigm(2.f * x), -1.f); }

// ---------------- prep: simple transposes + bf16 casts ----------------
__global__ __launch_bounds__(256) void prep_simple(
    const float* __restrict__ W1_0, const float* __restrict__ Wih0,
    const float* __restrict__ bih0, const float* __restrict__ bhh0,
    const float* __restrict__ W1_1, const float* __restrict__ Wih1,
    const float* __restrict__ bih1, const float* __restrict__ bhh1,
    const float* __restrict__ gmW, const float* __restrict__ fmW,
    unsigned short* __restrict__ W1T,  // [2][64*160] out-major
    unsigned short* __restrict__ WcT,  // [2][256*128] out-major (x-part cols 0..63)
    float* __restrict__ bG,            // [2][256]
    unsigned short* __restrict__ WrT)  // [128][64]
{
  int t = blockIdx.x * 256 + threadIdx.x;
  const int per = 10240 + 16384 + 256;  // 26880
  if (t >= 2 * per + 8192) return;
  if (t >= 2 * per) {
    int r2 = t - 2 * per;
    int o = r2 >> 6, k = r2 & 63;
    float v = 0.f;
    if (o < 50) v = gmW[k * 50 + o];
    else if (o >= 64 && o < 114) v = fmW[k * 50 + (o - 64)];
    WrT[o * 64 + k] = f2bf(v);
    return;
  }
  int step = t / per, r = t % per;
  const float* W1  = step ? W1_1 : W1_0;
  const float* Wih = step ? Wih1 : Wih0;
  const float* bih = step ? bih1 : bih0;
  const float* bhh = step ? bhh1 : bhh0;
  if (r < 10240) {
    int o = r / 160, k = r % 160;
    W1T[step * 10240 + o * 160 + k] = f2bf(W1[k * 64 + o]);
  } else if (r < 26624) {
    int rr = r - 10240;
    int g = rr >> 6, k = rr & 63;
    WcT[step * 32768 + g * 128 + k] = f2bf(Wih[k * 256 + g]);
  } else {
    int g = r - 26624;
    bG[step * 256 + g] = bih[g] + bhh[g];
  }
}

// ---------------- prep: merged weight  Wc_h' = W2 @ Whh,  b2h = b2 @ Whh ----------------
__global__ __launch_bounds__(256) void prep_merge(
    const float* __restrict__ W2_0, const float* __restrict__ Whh0, const float* __restrict__ b2_0,
    const float* __restrict__ W2_1, const float* __restrict__ Whh1, const float* __restrict__ b2_1,
    unsigned short* __restrict__ WcT,  // [2][256*128] (h-part cols 64..127)
    float* __restrict__ b2h)           // [2][256]
{
  int t = blockIdx.x * 256 + threadIdx.x;
  if (t < 32768) {
    int step = t >> 14, r = t & 16383;
    int g = r >> 6, k = r & 63;
    const float* W2  = step ? W2_1 : W2_0;
    const float* Whh = step ? Whh1 : Whh0;
    float v = 0.f;
    for (int j = 0; j < 64; ++j) v = fmaf(W2[k * 64 + j], Whh[j * 256 + g], v);
    WcT[step * 32768 + g * 128 + 64 + k] = f2bf(v);
  } else if (t < 33280) {
    int r = t - 32768;
    int step = r >> 8, g = r & 255;
    const float* b2  = step ? b2_1 : b2_0;
    const float* Whh = step ? Whh1 : Whh0;
    float v = 0.f;
    for (int j = 0; j < 64; ++j) v = fmaf(b2[j], Whh[j * 256 + g], v);
    b2h[step * 256 + g] = v;
  }
}

__global__ __launch_bounds__(256) void convert_x(
    const float* __restrict__ x, unsigned short* __restrict__ xb, int n)
{
  int i = blockIdx.x * 256 + threadIdx.x;
  if (i < n) xb[i] = f2bf(x[i]);
}

// ---------------- sort: hist -> scan(+segment build) -> scatter(+ea permute) ----------------
__global__ __launch_bounds__(256) void hist_kernel(
    const int* __restrict__ dstI, int* __restrict__ hist, int E)
{
  int e = blockIdx.x * 256 + threadIdx.x;
  if (e < E) atomicAdd(&hist[dstI[e]], 1);
}

__global__ __launch_bounds__(1024) void scan_seg(
    const int* __restrict__ hist, int* __restrict__ cursor,
    int4* __restrict__ segInfo, int* __restrict__ nSegTot, int N)
{
  __shared__ unsigned long long part[1024];
  int t = threadIdx.x;
  const int C = (N + 1023) >> 10;
  int n0 = t * C;
  unsigned long long acc = 0;
  for (int i = 0; i < C; ++i) {
    int n = n0 + i;
    if (n < N) {
      int d = hist[n];
      int sg = (d + 15) >> 4;
      acc += (((unsigned long long)sg) << 32) | (unsigned)d;
    }
  }
  part[t] = acc;
  __syncthreads();
  for (int off = 1; off < 1024; off <<= 1) {
    unsigned long long v = (t >= off) ? part[t - off] : 0ULL;
    __syncthreads();
    part[t] += v;
    __syncthreads();
  }
  unsigned long long run = t ? part[t - 1] : 0ULL;
  int runDeg = (int)(run & 0xFFFFFFFFULL);
  int runSeg = (int)(run >> 32);
  for (int i = 0; i < C; ++i) {
    int n = n0 + i;
    if (n < N) {
      int d = hist[n];
      cursor[n] = runDeg;
      int sg = (d + 15) >> 4;
      for (int j = 0; j < sg; ++j)
        segInfo[runSeg + j] = make_int4(runDeg + j * 16, n, min(d - j * 16, 16), 0);
      runDeg += d;
      runSeg += sg;
    }
  }
  if (t == 1023) *nSegTot = runSeg;
}

__global__ __launch_bounds__(256) void scatter_perm(
    const int* __restrict__ srcI, const int* __restrict__ dstI,
    const float* __restrict__ ea, int* __restrict__ cursor,
    int* __restrict__ srcS, unsigned short* __restrict__ eaS, int E)
{
  int e = blockIdx.x * 256 + threadIdx.x;
  if (e >= E) return;
  int d = dstI[e];
  int p = atomicAdd(&cursor[d], 1);
  srcS[p] = srcI[e];
  const float4* pe = (const float4*)(ea + (long long)e * 32);
  float4 a0 = pe[0], a1 = pe[1], a2 = pe[2], a3 = pe[3];
  float4 a4 = pe[4], a5 = pe[5], a6 = pe[6], a7 = pe[7];
  uint4* out = (uint4*)(eaS + (long long)p * 32);
  out[0] = make_uint4(pack2(a0.x, a0.y), pack2(a0.z, a0.w), pack2(a1.x, a1.y), pack2(a1.z, a1.w));
  out[1] = make_uint4(pack2(a2.x, a2.y), pack2(a2.z, a2.w), pack2(a3.x, a3.y), pack2(a3.z, a3.w));
  out[2] = make_uint4(pack2(a4.x, a4.y), pack2(a4.z, a4.w), pack2(a5.x, a5.y), pack2(a5.z, a5.w));
  out[3] = make_uint4(pack2(a6.x, a6.y), pack2(a6.z, a6.w), pack2(a7.x, a7.y), pack2(a7.z, a7.w));
}

// ---------------- edge GEMM + in-register aggregation ----------------
// wave = one 16-edge segment of one dst node. No barriers in the loop.
// aggrH[node][col] += sum over real rows of relu(m @ W1 + b1)
__global__ __launch_bounds__(256) void edge_gemm_agg(
    const unsigned short* __restrict__ xb,     // [N][64] bf16
    const unsigned short* __restrict__ eaS,    // [E][32] bf16, dst-sorted
    const int* __restrict__ srcS,              // [E] dst-sorted
    const int4* __restrict__ segInfo,          // [nSeg] {start,node,cnt,_}
    const int* __restrict__ nSegPtr,
    const unsigned short* __restrict__ W1T,    // [64][160] bf16 out-major
    const float* __restrict__ b1,
    float* __restrict__ aggrH)                 // [N][64] f32 (pre-zeroed)
{
  __shared__ unsigned short sM[64 * K1P];      // 4 wave-private 16-row regions
  __shared__ unsigned short sW1[64 * 21 * 8];  // 21 uint4/row padded
  __shared__ float sB1[64];
  const int t = threadIdx.x;
  {
    const uint4* gw1 = (const uint4*)W1T;      // 1280 uint4, 20/row
    uint4* lw1 = (uint4*)sW1;
    #pragma unroll
    for (int p = 0; p < 5; ++p) {
      int idx = t + p * 256;
      int o = idx / 20, s = idx % 20;
      lw1[o * 21 + s] = gw1[idx];
    }
    if (t < 64) sB1[t] = b1[t];
  }
  __syncthreads();

  const int w = t >> 6, l = t & 63;
  const int quad = l >> 4, lr = l & 15;
  const int r = l >> 2, q = l & 3;
  unsigned short* rowp = sM + (w * 16 + r) * K1P;
  const int nSeg = *nSegPtr;
  const int W = gridDim.x * 4;

  for (int s = blockIdx.x * 4 + w; s < nSeg; s += W) {
    int4 si = segInfo[s];
    const int start = si.x, node = si.y, cnt = si.z;

    // stage: [x[dst] | x[src] | ea]  (dst is wave-uniform)
    const uint4* pd = (const uint4*)(xb + (long long)node * 64);
    *(uint4*)(rowp + q * 16)     = pd[q * 2];
    *(uint4*)(rowp + q * 16 + 8) = pd[q * 2 + 1];
    int src = (r < cnt) ? srcS[start + r] : 0;
    const uint4* ps = (const uint4*)(xb + (long long)src * 64);
    *(uint4*)(rowp + 64 + q * 16)     = ps[q * 2];
    *(uint4*)(rowp + 64 + q * 16 + 8) = ps[q * 2 + 1];
    const uint4* pe = (const uint4*)(eaS + (long long)(start + r) * 32);
    *(uint4*)(rowp + 128 + q * 8) = pe[q];

    // GEMM1 (wave-private rows): h1 = m[16x160] @ W1[160x64]
    f32x4 acc[4] = {};
    #pragma unroll
    for (int kc = 0; kc < 5; ++kc) {
      short8 aF = *(const short8*)(sM + (w * 16 + lr) * K1P + kc * 32 + quad * 8);
      #pragma unroll
      for (int n = 0; n < 4; ++n) {
        short8 bF = *(const short8*)(sW1 + (n * 16 + lr) * K1P + kc * 32 + quad * 8);
        acc[n] = __builtin_amdgcn_mfma_f32_16x16x32_bf16(aF, bF, acc[n], 0, 0, 0);
      }
    }

    // relu + mask pads + reduce over the 16 rows -> one atomic per column
    #pragma unroll
    for (int n = 0; n < 4; ++n) {
      int col = n * 16 + lr;
      float bb = sB1[col];
      float sum = 0.f;
      #pragma unroll
      for (int rr = 0; rr < 4; ++rr) {
        int rowi = quad * 4 + rr;
        float v = fmaxf(acc[n][rr] + bb, 0.f);
        sum += (rowi < cnt) ? v : 0.f;
      }
      sum += __shfl_xor(sum, 16);
      sum += __shfl_xor(sum, 32);
      if (quad == 0) unsafeAtomicAdd(&aggrH[(long long)node * 64 + col], sum);
    }
  }
}

// ---------------- LSTM cell: gates = [x | G] @ Wc' + bG + deg*b2h ----------------
__global__ __launch_bounds__(256) void lstm3(
    const float* __restrict__ xin,
    const float* __restrict__ aggrH,          // [N][64] f32 (Sum relu h1)
    const float* __restrict__ cin,            // may be null (c=0)
    float* __restrict__ cout,
    const unsigned short* __restrict__ WcT,   // [256][128] bf16 out-major (merged)
    const float* __restrict__ bG,             // [256]
    const float* __restrict__ b2h,            // [256]
    const int* __restrict__ degA,             // [N]
    float* __restrict__ xout,
    unsigned short* __restrict__ xbf_out,     // may be null
    int nNodes)
{
  __shared__ unsigned short sIn[64 * KLP];
  __shared__ unsigned short sW[64 * KLP];
  __shared__ float sBG[256], sB2h[256];
  const int t = threadIdx.x;
  sBG[t] = bG[t];
  sB2h[t] = b2h[t];

  const int base_n = blockIdx.x * 64;
  const int nl = t >> 2, q = t & 3;
  const int node = base_n + nl;
  unsigned short* rowp = sIn + nl * KLP;
  if (node < nNodes) {
    const float4* px = (const float4*)(xin + (long long)node * 64) + q * 4;
    float4 v0 = px[0], v1 = px[1], v2 = px[2], v3 = px[3];
    *(uint4*)(rowp + q * 16) =
        make_uint4(pack2(v0.x, v0.y), pack2(v0.z, v0.w), pack2(v1.x, v1.y), pack2(v1.z, v1.w));
    *(uint4*)(rowp + q * 16 + 8) =
        make_uint4(pack2(v2.x, v2.y), pack2(v2.z, v2.w), pack2(v3.x, v3.y), pack2(v3.z, v3.w));
    const float4* pg = (const float4*)(aggrH + (long long)node * 64) + q * 4;
    float4 g0 = pg[0], g1 = pg[1], g2 = pg[2], g3 = pg[3];
    *(uint4*)(rowp + 64 + q * 16) =
        make_uint4(pack2(g0.x, g0.y), pack2(g0.z, g0.w), pack2(g1.x, g1.y), pack2(g1.z, g1.w));
    *(uint4*)(rowp + 64 + q * 16 + 8) =
        make_uint4(pack2(g2.x, g2.y), pack2(g2.z, g2.w), pack2(g3.x, g3.y), pack2(g3.z, g3.w));
  } else {
    *(uint4*)(rowp + q * 16)          = make_uint4(0, 0, 0, 0);
    *(uint4*)(rowp + q * 16 + 8)      = make_uint4(0, 0, 0, 0);
    *(uint4*)(rowp + 64 + q * 16)     = make_uint4(0, 0, 0, 0);
    *(uint4*)(rowp + 64 + q * 16 + 8) = make_uint4(0, 0, 0, 0);
  }

  const int w = t >> 6, l = t & 63, quad = l >> 4, lr = l & 15;
  const int row0 = w * 16;
  f32x4 acc[16] = {};
  for (int grp = 0; grp < 4; ++grp) {
    const uint4* gw = (const uint4*)WcT + (long long)(grp * 64) * 16;  // 16 uint4/row
    uint4* lw = (uint4*)sW;                                            // 17/row padded
    {
      int o0 = t >> 4, s4 = t & 15;
      #pragma unroll
      for (int p = 0; p < 4; ++p) {
        int o = p * 16 + o0;
        lw[o * 17 + s4] = gw[o * 16 + s4];
      }
    }
    __syncthreads();
    #pragma unroll
    for (int kc = 0; kc < 4; ++kc) {
      short8 aF = *(const short8*)(sIn + (row0 + lr) * KLP + kc * 32 + quad * 8);
      #pragma unroll
      for (int nt = 0; nt < 4; ++nt) {
        short8 bF = *(const short8*)(sW + (nt * 16 + lr) * KLP + kc * 32 + quad * 8);
        acc[grp * 4 + nt] = __builtin_amdgcn_mfma_f32_16x16x32_bf16(aF, bF, acc[grp * 4 + nt], 0, 0, 0);
      }
    }
    __syncthreads();
  }

  #pragma unroll
  for (int nt = 0; nt < 4; ++nt) {
    #pragma unroll
    for (int rr = 0; rr < 4; ++rr) {
      int node2 = base_n + row0 + quad * 4 + rr;
      if (node2 < nNodes) {
        int col = nt * 16 + lr;
        long long off = (long long)node2 * 64 + col;
        float dg = (float)degA[node2];
        float iv = acc[nt][rr]      + sBG[col]       + dg * sB2h[col];
        float fv = acc[4 + nt][rr]  + sBG[64 + col]  + dg * sB2h[64 + col];
        float gv = acc[8 + nt][rr]  + sBG[128 + col] + dg * sB2h[128 + col];
        float ov = acc[12 + nt][rr] + sBG[192 + col] + dg * sB2h[192 + col];
        float cOld = cin ? cin[off] : 0.f;
        float cN = sigm(fv) * cOld + sigm(iv) * tanh_f(gv);
        float hN = sigm(ov) * tanh_f(cN);
        cout[off] = cN;
        xout[off] = hN;
        if (xbf_out) xbf_out[off] = f2bf(hN);
      }
    }
  }
}

// ---------------- readout (MFMA) ----------------
__global__ __launch_bounds__(256) void readout(
    const float* __restrict__ x,
    const unsigned short* __restrict__ WrT,
    const float* __restrict__ gb, const float* __restrict__ fb,
    float* __restrict__ out, int nNodes)
{
  __shared__ unsigned short sX[64 * 72];
  __shared__ unsigned short sW[128 * 72];
  __shared__ float sOut[4][64];
  __shared__ float sGb[64], sFb[64];
  const int t = threadIdx.x;
  {
    const uint4* gw = (const uint4*)WrT;  // 1024 uint4
    uint4* lw = (uint4*)sW;               // 9/row padded
    #pragma unroll
    for (int p = 0; p < 4; ++p) {
      int idx = t + p * 256;
      int o = idx >> 3, s = idx & 7;
      lw[o * 9 + s] = gw[idx];
    }
    if (t < 50)      { sGb[t] = gb[t]; sFb[t] = fb[t]; }
    else if (t < 64) { sGb[t] = 0.f;   sFb[t] = 0.f; }
  }
  const int base = blockIdx.x * 64;
  const int nl = t >> 2, q = t & 3;
  const int node = base + nl;
  {
    uint2* dst = (uint2*)(sX + nl * 72 + q * 16);
    if (node < nNodes) {
      const float4* px = (const float4*)(x + (long long)node * 64) + q * 4;
      #pragma unroll
      for (int j = 0; j < 4; ++j) {
        float4 v = px[j];
        dst[j] = make_uint2(pack2(v.x, v.y), pack2(v.z, v.w));
      }
    } else {
      #pragma unroll
      for (int j = 0; j < 4; ++j) dst[j] = make_uint2(0, 0);
    }
  }
  __syncthreads();

  const int w = t >> 6, l = t & 63, quad = l >> 4, lr = l & 15;
  f32x4 acc[8] = {};
  #pragma unroll
  for (int kc = 0; kc < 2; ++kc) {
    short8 aF = *(const short8*)(sX + (w * 16 + lr) * 72 + kc * 32 + quad * 8);
    #pragma unroll
    for (int n = 0; n < 8; ++n) {
      short8 bF = *(const short8*)(sW + (n * 16 + lr) * 72 + kc * 32 + quad * 8);
      acc[n] = __builtin_amdgcn_mfma_f32_16x16x32_bf16(aF, bF, acc[n], 0, 0, 0);
    }
  }
  #pragma unroll
  for (int n = 0; n < 4; ++n) {
    float val = 0.f;
    #pragma unroll
    for (int rr = 0; rr < 4; ++rr) {
      int nd = base + w * 16 + quad * 4 + rr;
      if (nd < nNodes) {
        int jj = n * 16 + lr;
        float gv = sigm(acc[n][rr] + sGb[jj]);
        float fv = acc[n + 4][rr] + sFb[jj];
        val += gv * fv;
      }
    }
    val += __shfl_xor(val, 16);
    val += __shfl_xor(val, 32);
    if (quad == 0) sOut[w][n * 16 + lr] = val;
  }
  __syncthreads();
  if (t < 50) {
    float s = sOut[0][t] + sOut[1][t] + sOut[2][t] + sOut[3][t];
    unsafeAtomicAdd(&out[t], s);
  }
}

extern "C" void kernel_launch(void* const* d_in, const int* in_sizes, int n_in,
                              void* d_out, int out_size, void* d_ws, size_t ws_size,
                              hipStream_t stream)
{
  const float* x      = (const float*)d_in[0];
  const float* ea     = (const float*)d_in[1];
  const int*   ei     = (const int*)d_in[2];
  const float* fe0_W1 = (const float*)d_in[3];
  const float* fe0_b1 = (const float*)d_in[4];
  const float* fe0_W2 = (const float*)d_in[5];
  const float* fe0_b2 = (const float*)d_in[6];
  const float* l0_Wih = (const float*)d_in[7];
  const float* l0_Whh = (const float*)d_in[8];
  const float* l0_bih = (const float*)d_in[9];
  const float* l0_bhh = (const float*)d_in[10];
  const float* fe1_W1 = (const float*)d_in[11];
  const float* fe1_b1 = (const float*)d_in[12];
  const float* fe1_W2 = (const float*)d_in[13];
  const float* fe1_b2 = (const float*)d_in[14];
  const float* l1_Wih = (const float*)d_in[15];
  const float* l1_Whh = (const float*)d_in[16];
  const float* l1_bih = (const float*)d_in[17];
  const float* l1_bhh = (const float*)d_in[18];
  const float* gm_W   = (const float*)d_in[19];
  const float* gm_b   = (const float*)d_in[20];
  const float* fm_W   = (const float*)d_in[21];
  const float* fm_b   = (const float*)d_in[22];

  const int N = in_sizes[0] / 64;    // 50000
  const int E = in_sizes[1] / 32;    // 800000
  const int* srcI = ei;
  const int* dstI = ei + E;

  char* ws = (char*)d_ws;
  unsigned short* xb      = (unsigned short*)(ws + 0);           //  6,400,000
  float*          x1      = (float*)(ws + 6400000);              // 12,800,000
  float*          aggrH   = (float*)(ws + 19200000);             // 12,800,000
  float*          cbuf    = (float*)(ws + 32000000);             // 12,800,000
  unsigned short* eaS     = (unsigned short*)(ws + 44800000);    // 51,200,000 (+1KB slack)
  int*            srcS    = (int*)(ws + 96001024);               //  3,200,000 (+64 slack)
  int4*           segInfo = (int4*)(ws + 99201088);              //  1,600,128
  int*            histA   = (int*)(ws + 100801216);              //    200,000
  int*            curA    = (int*)(ws + 101001216);              //    200,000
  unsigned short* W1T     = (unsigned short*)(ws + 101201216);   //     40,960
  unsigned short* WcT     = (unsigned short*)(ws + 101242176);   //    131,072
  float*          bG      = (float*)(ws + 101373248);            //      2,048
  float*          b2h     = (float*)(ws + 101375296);            //      2,048
  unsigned short* WrT     = (unsigned short*)(ws + 101377344);   //     16,384
  int*            nSegPtr = (int*)(ws + 101393728);              //          4

  hipMemsetAsync(d_out, 0, out_size * sizeof(float), stream);
  hipMemsetAsync(histA, 0, (size_t)N * 4, stream);

  prep_simple<<<(2 * 26880 + 8192 + 255) / 256, 256, 0, stream>>>(
      fe0_W1, l0_Wih, l0_bih, l0_bhh,
      fe1_W1, l1_Wih, l1_bih, l1_bhh,
      gm_W, fm_W, W1T, WcT, bG, WrT);
  prep_merge<<<(33280 + 255) / 256, 256, 0, stream>>>(
      fe0_W2, l0_Whh, fe0_b2, fe1_W2, l1_Whh, fe1_b2, WcT, b2h);
  convert_x<<<(N * 64 + 255) / 256, 256, 0, stream>>>(x, xb, N * 64);

  hist_kernel<<<(E + 255) / 256, 256, 0, stream>>>(dstI, histA, E);
  scan_seg<<<1, 1024, 0, stream>>>(histA, curA, segInfo, nSegPtr, N);
  scatter_perm<<<(E + 255) / 256, 256, 0, stream>>>(srcI, dstI, ea, curA, srcS, eaS, E);

  const int nodeBlocks = (N + 63) / 64;

  // step 0
  hipMemsetAsync(aggrH, 0, (size_t)N * 64 * 4, stream);
  edge_gemm_agg<<<768, 256, 0, stream>>>(xb, eaS, srcS, segInfo, nSegPtr,
                                         W1T, fe0_b1, aggrH);
  lstm3<<<nodeBlocks, 256, 0, stream>>>(x, aggrH, nullptr, cbuf, WcT, bG, b2h,
                                        histA, x1, xb, N);

  // step 1
  hipMemsetAsync(aggrH, 0, (size_t)N * 64 * 4, stream);
  edge_gemm_agg<<<768, 256, 0, stream>>>(xb, eaS, srcS, segInfo, nSegPtr,
                                         W1T + 10240, fe1_b1, aggrH);
  lstm3<<<nodeBlocks, 256, 0, stream>>>(x1, aggrH, cbuf, cbuf, WcT + 32768,
                                        bG + 256, b2h + 256, histA, x1, nullptr, N);

  readout<<<nodeBlocks, 256, 0, stream>>>(x1, WrT, gm_b, fm_b, (float*)d_out, N);
}

// Round 5
// 490.851 us; speedup vs baseline: 1.7933x; 1.2399x over previous
//
#include <hip/hip_runtime.h>
#include <hip/hip_bf16.h>

using short8 = __attribute__((ext_vector_type(8))) short;
using f32x4  = __attribute__((ext_vector_type(4))) float;

#define K1P 168   // padded K=160 row stride (bf16) for edge MLP layer 1
#define KLP 136   // padded K=128 row stride for LSTM

__device__ __forceinline__ unsigned short f2bf(float f) {
  unsigned u = __float_as_uint(f);
  u += 0x7FFFu + ((u >> 16) & 1u);
  return (unsigned short)(u >> 16);
}
__device__ __forceinline__ unsigned pack2(float a, float b) {
  return (unsigned)f2bf(a) | ((unsigned)f2bf(b) << 16);
}
#if __has_builtin(__builtin_amdgcn_rcpf)
__device__ __forceinline__ float fast_rcp(float x) { return __builtin_amdgcn_rcpf(x); }
#else
__device__ __forceinline__ float fast_rcp(float x) { return 1.f / x; }
#endif
__device__ __forceinline__ float sigm(float x) { return fast_rcp(1.f + __expf(-x)); }
__device__ __forceinline__ float tanh_f(float x) { return fmaf(2.f, sigm(2.f * x), -1.f); }

// ---------------- prep: simple transposes + bf16 casts ----------------
__global__ __launch_bounds__(256) void prep_simple(
    const float* __restrict__ W1_0, const float* __restrict__ Wih0,
    const float* __restrict__ bih0, const float* __restrict__ bhh0,
    const float* __restrict__ W1_1, const float* __restrict__ Wih1,
    const float* __restrict__ bih1, const float* __restrict__ bhh1,
    const float* __restrict__ gmW, const float* __restrict__ fmW,
    unsigned short* __restrict__ W1T,  // [2][64*160] out-major
    unsigned short* __restrict__ WcT,  // [2][256*128] out-major (x-part cols 0..63)
    float* __restrict__ bG,            // [2][256]
    unsigned short* __restrict__ WrT)  // [128][64]
{
  int t = blockIdx.x * 256 + threadIdx.x;
  const int per = 10240 + 16384 + 256;  // 26880
  if (t >= 2 * per + 8192) return;
  if (t >= 2 * per) {
    int r2 = t - 2 * per;
    int o = r2 >> 6, k = r2 & 63;
    float v = 0.f;
    if (o < 50) v = gmW[k * 50 + o];
    else if (o >= 64 && o < 114) v = fmW[k * 50 + (o - 64)];
    WrT[o * 64 + k] = f2bf(v);
    return;
  }
  int step = t / per, r = t % per;
  const float* W1  = step ? W1_1 : W1_0;
  const float* Wih = step ? Wih1 : Wih0;
  const float* bih = step ? bih1 : bih0;
  const float* bhh = step ? bhh1 : bhh0;
  if (r < 10240) {
    int o = r / 160, k = r % 160;
    W1T[step * 10240 + o * 160 + k] = f2bf(W1[k * 64 + o]);
  } else if (r < 26624) {
    int rr = r - 10240;
    int g = rr >> 6, k = rr & 63;
    WcT[step * 32768 + g * 128 + k] = f2bf(Wih[k * 256 + g]);
  } else {
    int g = r - 26624;
    bG[step * 256 + g] = bih[g] + bhh[g];
  }
}

// ---------------- prep: merged weight  Wc_h' = W2 @ Whh,  b2h = b2 @ Whh ----------------
__global__ __launch_bounds__(256) void prep_merge(
    const float* __restrict__ W2_0, const float* __restrict__ Whh0, const float* __restrict__ b2_0,
    const float* __restrict__ W2_1, const float* __restrict__ Whh1, const float* __restrict__ b2_1,
    unsigned short* __restrict__ WcT,  // [2][256*128] (h-part cols 64..127)
    float* __restrict__ b2h)           // [2][256]
{
  int t = blockIdx.x * 256 + threadIdx.x;
  if (t < 32768) {
    int step = t >> 14, r = t & 16383;
    int g = r >> 6, k = r & 63;
    const float* W2  = step ? W2_1 : W2_0;
    const float* Whh = step ? Whh1 : Whh0;
    float v = 0.f;
    for (int j = 0; j < 64; ++j) v = fmaf(W2[k * 64 + j], Whh[j * 256 + g], v);
    WcT[step * 32768 + g * 128 + 64 + k] = f2bf(v);
  } else if (t < 33280) {
    int r = t - 32768;
    int step = r >> 8, g = r & 255;
    const float* b2  = step ? b2_1 : b2_0;
    const float* Whh = step ? Whh1 : Whh0;
    float v = 0.f;
    for (int j = 0; j < 64; ++j) v = fmaf(b2[j], Whh[j * 256 + g], v);
    b2h[step * 256 + g] = v;
  }
}

__global__ __launch_bounds__(256) void convert_x(
    const float* __restrict__ x, unsigned short* __restrict__ xb, int n)
{
  int i = blockIdx.x * 256 + threadIdx.x;
  if (i < n) xb[i] = f2bf(x[i]);
}

// ---------------- sort: hist -> 3-phase scan (+segment build) -> scatter ----------------
__global__ __launch_bounds__(256) void hist_kernel(
    const int* __restrict__ dstI, int* __restrict__ hist, int E)
{
  int e = blockIdx.x * 256 + threadIdx.x;
  if (e < E) atomicAdd(&hist[dstI[e]], 1);
}

// phase 1: per-block totals of (deg, segCount)
__global__ __launch_bounds__(256) void scan_part(
    const int* __restrict__ hist, int2* __restrict__ blockTot, int N)
{
  __shared__ int sD[256], sS[256];
  int t = threadIdx.x;
  int n = blockIdx.x * 256 + t;
  int d = (n < N) ? hist[n] : 0;
  int sg = (d + 15) >> 4;
  sD[t] = d; sS[t] = sg;
  __syncthreads();
  #pragma unroll
  for (int off = 128; off; off >>= 1) {
    if (t < off) { sD[t] += sD[t + off]; sS[t] += sS[t + off]; }
    __syncthreads();
  }
  if (t == 0) blockTot[blockIdx.x] = make_int2(sD[0], sS[0]);
}

// phase 2: exclusive scan of block totals (nb <= 256)
__global__ __launch_bounds__(256) void scan_mid(
    const int2* __restrict__ blockTot, int2* __restrict__ blockBase,
    int* __restrict__ nSegTot, int nb)
{
  __shared__ int sD[256], sS[256];
  int t = threadIdx.x;
  int d = 0, s = 0;
  if (t < nb) { int2 v = blockTot[t]; d = v.x; s = v.y; }
  sD[t] = d; sS[t] = s;
  __syncthreads();
  #pragma unroll
  for (int off = 1; off < 256; off <<= 1) {
    int vd = (t >= off) ? sD[t - off] : 0;
    int vs = (t >= off) ? sS[t - off] : 0;
    __syncthreads();
    sD[t] += vd; sS[t] += vs;
    __syncthreads();
  }
  if (t < nb) blockBase[t] = make_int2(sD[t] - d, sS[t] - s);
  if (t == nb - 1) *nSegTot = sS[t];
}

// phase 3: per-block scan + write cursor and segInfo (1 node/thread)
__global__ __launch_bounds__(256) void scan_final(
    const int* __restrict__ hist, const int2* __restrict__ blockBase,
    int* __restrict__ cursor, int4* __restrict__ segInfo, int N)
{
  __shared__ int sD[256], sS[256];
  int t = threadIdx.x;
  int n = blockIdx.x * 256 + t;
  int d = (n < N) ? hist[n] : 0;
  int sg = (d + 15) >> 4;
  sD[t] = d; sS[t] = sg;
  __syncthreads();
  #pragma unroll
  for (int off = 1; off < 256; off <<= 1) {
    int vd = (t >= off) ? sD[t - off] : 0;
    int vs = (t >= off) ? sS[t - off] : 0;
    __syncthreads();
    sD[t] += vd; sS[t] += vs;
    __syncthreads();
  }
  if (n < N) {
    int2 bb = blockBase[blockIdx.x];
    int degBase = bb.x + sD[t] - d;
    int segBase = bb.y + sS[t] - sg;
    cursor[n] = degBase;
    for (int j = 0; j < sg; ++j)
      segInfo[segBase + j] = make_int4(degBase + j * 16, n, min(d - j * 16, 16), 0);
  }
}

__global__ __launch_bounds__(256) void scatter_perm(
    const int* __restrict__ srcI, const int* __restrict__ dstI,
    const float* __restrict__ ea, int* __restrict__ cursor,
    int* __restrict__ srcS, unsigned short* __restrict__ eaS, int E)
{
  int e = blockIdx.x * 256 + threadIdx.x;
  if (e >= E) return;
  int d = dstI[e];
  int p = atomicAdd(&cursor[d], 1);
  srcS[p] = srcI[e];
  const float4* pe = (const float4*)(ea + (long long)e * 32);
  float4 a0 = pe[0], a1 = pe[1], a2 = pe[2], a3 = pe[3];
  float4 a4 = pe[4], a5 = pe[5], a6 = pe[6], a7 = pe[7];
  uint4* out = (uint4*)(eaS + (long long)p * 32);
  out[0] = make_uint4(pack2(a0.x, a0.y), pack2(a0.z, a0.w), pack2(a1.x, a1.y), pack2(a1.z, a1.w));
  out[1] = make_uint4(pack2(a2.x, a2.y), pack2(a2.z, a2.w), pack2(a3.x, a3.y), pack2(a3.z, a3.w));
  out[2] = make_uint4(pack2(a4.x, a4.y), pack2(a4.z, a4.w), pack2(a5.x, a5.y), pack2(a5.z, a5.w));
  out[3] = make_uint4(pack2(a6.x, a6.y), pack2(a6.z, a6.w), pack2(a7.x, a7.y), pack2(a7.z, a7.w));
}

// ---------------- edge GEMM + in-register aggregation ----------------
// wave = one 16-edge segment of one dst node. No barriers in the loop.
__global__ __launch_bounds__(256) void edge_gemm_agg(
    const unsigned short* __restrict__ xb,     // [N][64] bf16
    const unsigned short* __restrict__ eaS,    // [E][32] bf16, dst-sorted
    const int* __restrict__ srcS,              // [E] dst-sorted
    const int4* __restrict__ segInfo,          // [nSeg] {start,node,cnt,_}
    const int* __restrict__ nSegPtr,
    const unsigned short* __restrict__ W1T,    // [64][160] bf16 out-major
    const float* __restrict__ b1,
    float* __restrict__ aggrH)                 // [N][64] f32 (pre-zeroed)
{
  __shared__ unsigned short sM[64 * K1P];      // 4 wave-private 16-row regions
  __shared__ unsigned short sW1[64 * 21 * 8];  // 21 uint4/row padded
  __shared__ float sB1[64];
  const int t = threadIdx.x;
  {
    const uint4* gw1 = (const uint4*)W1T;      // 1280 uint4, 20/row
    uint4* lw1 = (uint4*)sW1;
    #pragma unroll
    for (int p = 0; p < 5; ++p) {
      int idx = t + p * 256;
      int o = idx / 20, s = idx % 20;
      lw1[o * 21 + s] = gw1[idx];
    }
    if (t < 64) sB1[t] = b1[t];
  }
  __syncthreads();

  const int w = t >> 6, l = t & 63;
  const int quad = l >> 4, lr = l & 15;
  const int r = l >> 2, q = l & 3;
  unsigned short* rowp = sM + (w * 16 + r) * K1P;
  const int nSeg = *nSegPtr;
  const int W = gridDim.x * 4;

  for (int s = blockIdx.x * 4 + w; s < nSeg; s += W) {
    int4 si = segInfo[s];
    const int start = si.x, node = si.y, cnt = si.z;

    // stage: [x[dst] | x[src] | ea]  (dst is wave-uniform)
    const uint4* pd = (const uint4*)(xb + (long long)node * 64);
    *(uint4*)(rowp + q * 16)     = pd[q * 2];
    *(uint4*)(rowp + q * 16 + 8) = pd[q * 2 + 1];
    int src = (r < cnt) ? srcS[start + r] : 0;
    const uint4* ps = (const uint4*)(xb + (long long)src * 64);
    *(uint4*)(rowp + 64 + q * 16)     = ps[q * 2];
    *(uint4*)(rowp + 64 + q * 16 + 8) = ps[q * 2 + 1];
    const uint4* pe = (const uint4*)(eaS + (long long)(start + r) * 32);
    *(uint4*)(rowp + 128 + q * 8) = pe[q];

    // GEMM1 (wave-private rows): h1 = m[16x160] @ W1[160x64]
    f32x4 acc[4] = {};
    #pragma unroll
    for (int kc = 0; kc < 5; ++kc) {
      short8 aF = *(const short8*)(sM + (w * 16 + lr) * K1P + kc * 32 + quad * 8);
      #pragma unroll
      for (int n = 0; n < 4; ++n) {
        short8 bF = *(const short8*)(sW1 + (n * 16 + lr) * K1P + kc * 32 + quad * 8);
        acc[n] = __builtin_amdgcn_mfma_f32_16x16x32_bf16(aF, bF, acc[n], 0, 0, 0);
      }
    }

    // relu + mask pads + reduce over the 16 rows -> one atomic per column
    #pragma unroll
    for (int n = 0; n < 4; ++n) {
      int col = n * 16 + lr;
      float bb = sB1[col];
      float sum = 0.f;
      #pragma unroll
      for (int rr = 0; rr < 4; ++rr) {
        int rowi = quad * 4 + rr;
        float v = fmaxf(acc[n][rr] + bb, 0.f);
        sum += (rowi < cnt) ? v : 0.f;
      }
      sum += __shfl_xor(sum, 16);
      sum += __shfl_xor(sum, 32);
      if (quad == 0) unsafeAtomicAdd(&aggrH[(long long)node * 64 + col], sum);
    }
  }
}

// ---------------- LSTM cell: gates = [x | G] @ Wc' + bG + deg*b2h ----------------
__global__ __launch_bounds__(256) void lstm3(
    const float* __restrict__ xin,
    const float* __restrict__ aggrH,          // [N][64] f32 (Sum relu h1)
    const float* __restrict__ cin,            // may be null (c=0)
    float* __restrict__ cout,
    const unsigned short* __restrict__ WcT,   // [256][128] bf16 out-major (merged)
    const float* __restrict__ bG,             // [256]
    const float* __restrict__ b2h,            // [256]
    const int* __restrict__ degA,             // [N]
    float* __restrict__ xout,
    unsigned short* __restrict__ xbf_out,     // may be null
    int nNodes)
{
  __shared__ unsigned short sIn[64 * KLP];
  __shared__ unsigned short sW[64 * KLP];
  __shared__ float sBG[256], sB2h[256];
  const int t = threadIdx.x;
  sBG[t] = bG[t];
  sB2h[t] = b2h[t];

  const int base_n = blockIdx.x * 64;
  const int nl = t >> 2, q = t & 3;
  const int node = base_n + nl;
  unsigned short* rowp = sIn + nl * KLP;
  if (node < nNodes) {
    const float4* px = (const float4*)(xin + (long long)node * 64) + q * 4;
    float4 v0 = px[0], v1 = px[1], v2 = px[2], v3 = px[3];
    *(uint4*)(rowp + q * 16) =
        make_uint4(pack2(v0.x, v0.y), pack2(v0.z, v0.w), pack2(v1.x, v1.y), pack2(v1.z, v1.w));
    *(uint4*)(rowp + q * 16 + 8) =
        make_uint4(pack2(v2.x, v2.y), pack2(v2.z, v2.w), pack2(v3.x, v3.y), pack2(v3.z, v3.w));
    const float4* pg = (const float4*)(aggrH + (long long)node * 64) + q * 4;
    float4 g0 = pg[0], g1 = pg[1], g2 = pg[2], g3 = pg[3];
    *(uint4*)(rowp + 64 + q * 16) =
        make_uint4(pack2(g0.x, g0.y), pack2(g0.z, g0.w), pack2(g1.x, g1.y), pack2(g1.z, g1.w));
    *(uint4*)(rowp + 64 + q * 16 + 8) =
        make_uint4(pack2(g2.x, g2.y), pack2(g2.z, g2.w), pack2(g3.x, g3.y), pack2(g3.z, g3.w));
  } else {
    *(uint4*)(rowp + q * 16)          = make_uint4(0, 0, 0, 0);
    *(uint4*)(rowp + q * 16 + 8)      = make_uint4(0, 0, 0, 0);
    *(uint4*)(rowp + 64 + q * 16)     = make_uint4(0, 0, 0, 0);
    *(uint4*)(rowp + 64 + q * 16 + 8) = make_uint4(0, 0, 0, 0);
  }

  const int w = t >> 6, l = t & 63, quad = l >> 4, lr = l & 15;
  const int row0 = w * 16;
  f32x4 acc[16] = {};
  for (int grp = 0; grp < 4; ++grp) {
    const uint4* gw = (const uint4*)WcT + (long long)(grp * 64) * 16;  // 16 uint4/row
    uint4* lw = (uint4*)sW;                                            // 17/row padded
    {
      int o0 = t >> 4, s4 = t & 15;
      #pragma unroll
      for (int p = 0; p < 4; ++p) {
        int o = p * 16 + o0;
        lw[o * 17 + s4] = gw[o * 16 + s4];
      }
    }
    __syncthreads();
    #pragma unroll
    for (int kc = 0; kc < 4; ++kc) {
      short8 aF = *(const short8*)(sIn + (row0 + lr) * KLP + kc * 32 + quad * 8);
      #pragma unroll
      for (int nt = 0; nt < 4; ++nt) {
        short8 bF = *(const short8*)(sW + (nt * 16 + lr) * KLP + kc * 32 + quad * 8);
        acc[grp * 4 + nt] = __builtin_amdgcn_mfma_f32_16x16x32_bf16(aF, bF, acc[grp * 4 + nt], 0, 0, 0);
      }
    }
    __syncthreads();
  }

  #pragma unroll
  for (int nt = 0; nt < 4; ++nt) {
    #pragma unroll
    for (int rr = 0; rr < 4; ++rr) {
      int node2 = base_n + row0 + quad * 4 + rr;
      if (node2 < nNodes) {
        int col = nt * 16 + lr;
        long long off = (long long)node2 * 64 + col;
        float dg = (float)degA[node2];
        float iv = acc[nt][rr]      + sBG[col]       + dg * sB2h[col];
        float fv = acc[4 + nt][rr]  + sBG[64 + col]  + dg * sB2h[64 + col];
        float gv = acc[8 + nt][rr]  + sBG[128 + col] + dg * sB2h[128 + col];
        float ov = acc[12 + nt][rr] + sBG[192 + col] + dg * sB2h[192 + col];
        float cOld = cin ? cin[off] : 0.f;
        float cN = sigm(fv) * cOld + sigm(iv) * tanh_f(gv);
        float hN = sigm(ov) * tanh_f(cN);
        cout[off] = cN;
        xout[off] = hN;
        if (xbf_out) xbf_out[off] = f2bf(hN);
      }
    }
  }
}

// ---------------- readout (MFMA) ----------------
__global__ __launch_bounds__(256) void readout(
    const float* __restrict__ x,
    const unsigned short* __restrict__ WrT,
    const float* __restrict__ gb, const float* __restrict__ fb,
    float* __restrict__ out, int nNodes)
{
  __shared__ unsigned short sX[64 * 72];
  __shared__ unsigned short sW[128 * 72];
  __shared__ float sOut[4][64];
  __shared__ float sGb[64], sFb[64];
  const int t = threadIdx.x;
  {
    const uint4* gw = (const uint4*)WrT;  // 1024 uint4
    uint4* lw = (uint4*)sW;               // 9/row padded
    #pragma unroll
    for (int p = 0; p < 4; ++p) {
      int idx = t + p * 256;
      int o = idx >> 3, s = idx & 7;
      lw[o * 9 + s] = gw[idx];
    }
    if (t < 50)      { sGb[t] = gb[t]; sFb[t] = fb[t]; }
    else if (t < 64) { sGb[t] = 0.f;   sFb[t] = 0.f; }
  }
  const int base = blockIdx.x * 64;
  const int nl = t >> 2, q = t & 3;
  const int node = base + nl;
  {
    uint2* dst = (uint2*)(sX + nl * 72 + q * 16);
    if (node < nNodes) {
      const float4* px = (const float4*)(x + (long long)node * 64) + q * 4;
      #pragma unroll
      for (int j = 0; j < 4; ++j) {
        float4 v = px[j];
        dst[j] = make_uint2(pack2(v.x, v.y), pack2(v.z, v.w));
      }
    } else {
      #pragma unroll
      for (int j = 0; j < 4; ++j) dst[j] = make_uint2(0, 0);
    }
  }
  __syncthreads();

  const int w = t >> 6, l = t & 63, quad = l >> 4, lr = l & 15;
  f32x4 acc[8] = {};
  #pragma unroll
  for (int kc = 0; kc < 2; ++kc) {
    short8 aF = *(const short8*)(sX + (w * 16 + lr) * 72 + kc * 32 + quad * 8);
    #pragma unroll
    for (int n = 0; n < 8; ++n) {
      short8 bF = *(const short8*)(sW + (n * 16 + lr) * 72 + kc * 32 + quad * 8);
      acc[n] = __builtin_amdgcn_mfma_f32_16x16x32_bf16(aF, bF, acc[n], 0, 0, 0);
    }
  }
  #pragma unroll
  for (int n = 0; n < 4; ++n) {
    float val = 0.f;
    #pragma unroll
    for (int rr = 0; rr < 4; ++rr) {
      int nd = base + w * 16 + quad * 4 + rr;
      if (nd < nNodes) {
        int jj = n * 16 + lr;
        float gv = sigm(acc[n][rr] + sGb[jj]);
        float fv = acc[n + 4][rr] + sFb[jj];
        val += gv * fv;
      }
    }
    val += __shfl_xor(val, 16);
    val += __shfl_xor(val, 32);
    if (quad == 0) sOut[w][n * 16 + lr] = val;
  }
  __syncthreads();
  if (t < 50) {
    float s = sOut[0][t] + sOut[1][t] + sOut[2][t] + sOut[3][t];
    unsafeAtomicAdd(&out[t], s);
  }
}

extern "C" void kernel_launch(void* const* d_in, const int* in_sizes, int n_in,
                              void* d_out, int out_size, void* d_ws, size_t ws_size,
                              hipStream_t stream)
{
  const float* x      = (const float*)d_in[0];
  const float* ea     = (const float*)d_in[1];
  const int*   ei     = (const int*)d_in[2];
  const float* fe0_W1 = (const float*)d_in[3];
  const float* fe0_b1 = (const float*)d_in[4];
  const float* fe0_W2 = (const float*)d_in[5];
  const float* fe0_b2 = (const float*)d_in[6];
  const float* l0_Wih = (const float*)d_in[7];
  const float* l0_Whh = (const float*)d_in[8];
  const float* l0_bih = (const float*)d_in[9];
  const float* l0_bhh = (const float*)d_in[10];
  const float* fe1_W1 = (const float*)d_in[11];
  const float* fe1_b1 = (const float*)d_in[12];
  const float* fe1_W2 = (const float*)d_in[13];
  const float* fe1_b2 = (const float*)d_in[14];
  const float* l1_Wih = (const float*)d_in[15];
  const float* l1_Whh = (const float*)d_in[16];
  const float* l1_bih = (const float*)d_in[17];
  const float* l1_bhh = (const float*)d_in[18];
  const float* gm_W   = (const float*)d_in[19];
  const float* gm_b   = (const float*)d_in[20];
  const float* fm_W   = (const float*)d_in[21];
  const float* fm_b   = (const float*)d_in[22];

  const int N = in_sizes[0] / 64;    // 50000
  const int E = in_sizes[1] / 32;    // 800000
  const int* srcI = ei;
  const int* dstI = ei + E;

  char* ws = (char*)d_ws;
  unsigned short* xb      = (unsigned short*)(ws + 0);           //  6,400,000
  float*          x1      = (float*)(ws + 6400000);              // 12,800,000
  float*          aggrH   = (float*)(ws + 19200000);             // 12,800,000
  float*          cbuf    = (float*)(ws + 32000000);             // 12,800,000
  unsigned short* eaS     = (unsigned short*)(ws + 44800000);    // 51,200,000 (+1KB slack)
  int*            srcS    = (int*)(ws + 96001024);               //  3,200,000 (+64 slack)
  int4*           segInfo = (int4*)(ws + 99201088);              //  1,600,128
  int*            histA   = (int*)(ws + 100801216);              //    200,000
  int*            curA    = (int*)(ws + 101001216);              //    200,000
  unsigned short* W1T     = (unsigned short*)(ws + 101201216);   //     40,960
  unsigned short* WcT     = (unsigned short*)(ws + 101242176);   //    131,072
  float*          bG      = (float*)(ws + 101373248);            //      2,048
  float*          b2h     = (float*)(ws + 101375296);            //      2,048
  unsigned short* WrT     = (unsigned short*)(ws + 101377344);   //     16,384
  int*            nSegPtr = (int*)(ws + 101393728);              //          4 (+60 pad)
  int2*           blockTot  = (int2*)(ws + 101393792);           //      2,048
  int2*           blockBase = (int2*)(ws + 101395840);           //      2,048

  hipMemsetAsync(d_out, 0, out_size * sizeof(float), stream);
  hipMemsetAsync(histA, 0, (size_t)N * 4, stream);

  prep_simple<<<(2 * 26880 + 8192 + 255) / 256, 256, 0, stream>>>(
      fe0_W1, l0_Wih, l0_bih, l0_bhh,
      fe1_W1, l1_Wih, l1_bih, l1_bhh,
      gm_W, fm_W, W1T, WcT, bG, WrT);
  prep_merge<<<(33280 + 255) / 256, 256, 0, stream>>>(
      fe0_W2, l0_Whh, fe0_b2, fe1_W2, l1_Whh, fe1_b2, WcT, b2h);
  convert_x<<<(N * 64 + 255) / 256, 256, 0, stream>>>(x, xb, N * 64);

  const int nb = (N + 255) / 256;  // 196 <= 256
  hist_kernel<<<(E + 255) / 256, 256, 0, stream>>>(dstI, histA, E);
  scan_part<<<nb, 256, 0, stream>>>(histA, blockTot, N);
  scan_mid<<<1, 256, 0, stream>>>(blockTot, blockBase, nSegPtr, nb);
  scan_final<<<nb, 256, 0, stream>>>(histA, blockBase, curA, segInfo, N);
  scatter_perm<<<(E + 255) / 256, 256, 0, stream>>>(srcI, dstI, ea, curA, srcS, eaS, E);

  const int nodeBlocks = (N + 63) / 64;

  // step 0
  hipMemsetAsync(aggrH, 0, (size_t)N * 64 * 4, stream);
  edge_gemm_agg<<<768, 256, 0, stream>>>(xb, eaS, srcS, segInfo, nSegPtr,
                                         W1T, fe0_b1, aggrH);
  lstm3<<<nodeBlocks, 256, 0, stream>>>(x, aggrH, nullptr, cbuf, WcT, bG, b2h,
                                        histA, x1, xb, N);

  // step 1
  hipMemsetAsync(aggrH, 0, (size_t)N * 64 * 4, stream);
  edge_gemm_agg<<<768, 256, 0, stream>>>(xb, eaS, srcS, segInfo, nSegPtr,
                                         W1T + 10240, fe1_b1, aggrH);
  lstm3<<<nodeBlocks, 256, 0, stream>>>(x1, aggrH, cbuf, cbuf, WcT + 32768,
                                        bG + 256, b2h + 256, histA, x1, nullptr, N);

  readout<<<nodeBlocks, 256, 0, stream>>>(x1, WrT, gm_b, fm_b, (float*)d_out, N);
}